// Round 8
// baseline (129.597 us; speedup 1.0000x reference)
//
#include <hip/hip_runtime.h>
#include <hip/hip_bf16.h>

#define ALPHA 0.2f
#define NEG_BIG -1e12f
#define LOG2E 1.44269504088896340736f

constexpr int B_ = 8, N_ = 2048, C_ = 128;
constexpr int SPLIT = 4;                 // j-chunks per i-group (8 waves/block)
constexpr int JPC = N_ / SPLIT;          // 512 j per chunk
constexpr int JB = 128, NJT = JPC / JB;  // 4 iterations per wave

typedef __attribute__((ext_vector_type(8))) short short8;
typedef __attribute__((ext_vector_type(8))) unsigned short ushort8;
typedef __attribute__((ext_vector_type(4))) float f32x4;

__device__ __forceinline__ unsigned short f2bf(float f) {
    unsigned int u = __float_as_uint(f);
    u += 0x7fffu + ((u >> 16) & 1u);
    return (unsigned short)(u >> 16);
}

__device__ __forceinline__ unsigned int cvtpk_bf16(float lo, float hi) {
    unsigned int r;
    asm("v_cvt_pk_bf16_f32 %0, %1, %2" : "=v"(r) : "v"(lo), "v"(hi));
    return r;
}

// ---------------------------------------------------------------------------
// Kernel 1: hidden = x @ W (f32, exact), emit hiddenT bf16 [B, C, N] and
// attn1/attn2 = (hidden @ a) * LOG2E  (log2-domain logits for exp2 softmax).
// ---------------------------------------------------------------------------
__global__ __launch_bounds__(256) void k1_hidden(
    const float* __restrict__ x, const float* __restrict__ W,
    const float* __restrict__ a, unsigned short* __restrict__ hT,
    float* __restrict__ at1, float* __restrict__ at2)
{
    __shared__ float xs[64][C_];   // 32 KB
    __shared__ float Ws[C_][C_];   // 64 KB
    const int tid = threadIdx.x;
    const int row0 = blockIdx.x * 64;   // global row = b*N + n

    {
        const float4* xsrc = (const float4*)(x + (size_t)row0 * C_);
        float4* xdst = (float4*)&xs[0][0];
        for (int i = tid; i < 64 * C_ / 4; i += 256) xdst[i] = xsrc[i];
        const float4* wsrc = (const float4*)W;
        float4* wdst = (float4*)&Ws[0][0];
        for (int i = tid; i < C_ * C_ / 4; i += 256) wdst[i] = wsrc[i];
    }
    __syncthreads();

    const int tr = tid >> 5, tc = tid & 31;
    const int r0 = tr * 8, c0 = tc * 4;

    float acc[8][4];
#pragma unroll
    for (int i = 0; i < 8; ++i)
#pragma unroll
        for (int j = 0; j < 4; ++j) acc[i][j] = 0.f;

    for (int k = 0; k < C_; k += 4) {
        float4 w0 = *(const float4*)&Ws[k + 0][c0];
        float4 w1 = *(const float4*)&Ws[k + 1][c0];
        float4 w2 = *(const float4*)&Ws[k + 2][c0];
        float4 w3 = *(const float4*)&Ws[k + 3][c0];
#pragma unroll
        for (int rr = 0; rr < 8; ++rr) {
            float4 xv = *(const float4*)&xs[r0 + rr][k];
            acc[rr][0] += xv.x * w0.x + xv.y * w1.x + xv.z * w2.x + xv.w * w3.x;
            acc[rr][1] += xv.x * w0.y + xv.y * w1.y + xv.z * w2.y + xv.w * w3.y;
            acc[rr][2] += xv.x * w0.z + xv.y * w1.z + xv.z * w2.z + xv.w * w3.z;
            acc[rr][3] += xv.x * w0.w + xv.y * w1.w + xv.z * w2.w + xv.w * w3.w;
        }
    }

    float av0[4], av1[4];
#pragma unroll
    for (int cc = 0; cc < 4; ++cc) {
        av0[cc] = a[(c0 + cc) * 2 + 0];
        av1[cc] = a[(c0 + cc) * 2 + 1];
    }
#pragma unroll
    for (int rr = 0; rr < 8; ++rr) {
        float s1 = acc[rr][0] * av0[0] + acc[rr][1] * av0[1] +
                   acc[rr][2] * av0[2] + acc[rr][3] * av0[3];
        float s2 = acc[rr][0] * av1[0] + acc[rr][1] * av1[1] +
                   acc[rr][2] * av1[2] + acc[rr][3] * av1[3];
#pragma unroll
        for (int off = 1; off < 32; off <<= 1) {
            s1 += __shfl_xor(s1, off);
            s2 += __shfl_xor(s2, off);
        }
        if (tc == 0) {
            at1[row0 + r0 + rr] = s1 * LOG2E;
            at2[row0 + r0 + rr] = s2 * LOG2E;
        }
    }

    const int b = row0 >> 11;
    const int n0 = row0 & (N_ - 1);
#pragma unroll
    for (int cc = 0; cc < 4; ++cc) {
        ushort8 hv;
#pragma unroll
        for (int rr = 0; rr < 8; ++rr) hv[rr] = f2bf(acc[rr][cc]);
        *(ushort8*)(hT + ((size_t)b * C_ + c0 + cc) * N_ + n0 + r0) = hv;
    }
}

// ---------------------------------------------------------------------------
// Kernel 2: split-j flash attention.  Block = 512 threads = 8 waves
// = (sp: 4 j-chunks) x (wv: 2 c-halves).  Each wave runs a barrier-free
// 4-iteration flash loop over its 512-j chunk with lane-local (m,l,acc):
// lane (r=lane&15, jc=lane>>4) owns softmax row r for j = chunk + ks*32 +
// jc*8 + e (the MFMA B-fragment layout).  Swapped MFMA (A=hT, B=P) gives
// C/D col = r (i-row), row = jc*4+reg (c).  At the end: one barrier, then
// log-sum-exp merge of the 4 chunk-partials through LDS.
// ---------------------------------------------------------------------------
__global__ __launch_bounds__(512, 4) void k2_attn(
    const int* __restrict__ adj, const unsigned short* __restrict__ hT,
    const float* __restrict__ at1, const float* __restrict__ at2,
    const float* __restrict__ bias, float* __restrict__ out)
{
    __shared__ float at2s[N_];                    // 8 KB
    __shared__ float accLds[SPLIT][16][C_];       // 32 KB
    __shared__ float mlm[SPLIT][16], mll[SPLIT][16];

    const int tid = threadIdx.x;
    const int b  = blockIdx.x >> 7;               // 128 i-groups per batch
    const int i0 = (blockIdx.x & 127) * 16;

    // stage at2[b,:] (log2-scaled) into LDS: 512 threads x 16B = 8 KB
    ((float4*)at2s)[tid] = ((const float4*)(at2 + (size_t)b * N_))[tid];

    const int lane = tid & 63;
    const int w   = tid >> 6;                     // 0..7
    const int sp  = w >> 1;                       // j-chunk 0..3
    const int wv  = w & 1;                        // c-half 0/1
    const int r   = lane & 15;                    // softmax row (= C/D col)
    const int jc  = lane >> 4;                    // 0..3
    const int jb0 = sp * JPC;

    const float a1v = at1[(size_t)b * N_ + i0 + r];
    const int* arow = adj + ((size_t)(b * N_ + i0 + r)) * N_ + jb0 + jc * 8;
    const unsigned short* hrow =
        hT + ((size_t)b * C_ + wv * 64 + r) * N_ + jb0 + jc * 8;

    f32x4 acc[4];
#pragma unroll
    for (int cb = 0; cb < 4; ++cb) acc[cb] = (f32x4){0.f, 0.f, 0.f, 0.f};
    float m = -3e38f, l = 0.f;

    __syncthreads();   // at2s visible; no barriers until the merge

    // adj prefetch for jt=0: A[q], q = ks*2+h -> j = ks*32 + jc*8 + h*4 + e
    int4 A[8];
#pragma unroll
    for (int q = 0; q < 8; ++q)
        A[q] = *(const int4*)(arow + (q >> 1) * 32 + (q & 1) * 4);

    for (int jt = 0; jt < NJT; ++jt) {
        const int j0 = jt * JB;

        // hT A-fragments first (MFMA's vmcnt wait must not force An to retire)
        short8 h0[4], h1[4], h2[4], h3[4];
#pragma unroll
        for (int ks = 0; ks < 4; ++ks) {
            h0[ks] = *(const short8*)(hrow + j0 + ks * 32);
            h1[ks] = *(const short8*)(hrow + (size_t)16 * N_ + j0 + ks * 32);
            h2[ks] = *(const short8*)(hrow + (size_t)32 * N_ + j0 + ks * 32);
            h3[ks] = *(const short8*)(hrow + (size_t)48 * N_ + j0 + ks * 32);
        }

        // next-tile adj prefetch (issued last -> stays in flight across MFMA)
        const int jn = (jt + 1 < NJT ? jt + 1 : jt) * JB;
        int4 An[8];
#pragma unroll
        for (int q = 0; q < 8; ++q)
            An[q] = *(const int4*)(arow + jn + (q >> 1) * 32 + (q & 1) * 4);

        // at2 for this tile from LDS (log2 domain)
        float4 F[8];
#pragma unroll
        for (int q = 0; q < 8; ++q)
            F[q] = *(const float4*)&at2s[jb0 + j0 + (q >> 1) * 32 + jc * 8 + (q & 1) * 4];

        // logits: leaky in log2 domain (leaky commutes with positive scale)
        float p[32];
#pragma unroll
        for (int q = 0; q < 8; ++q) {
            float t;
            t = a1v + F[q].x; t = fmaxf(t, ALPHA * t); p[q * 4 + 0] = A[q].x > 0 ? t : NEG_BIG;
            t = a1v + F[q].y; t = fmaxf(t, ALPHA * t); p[q * 4 + 1] = A[q].y > 0 ? t : NEG_BIG;
            t = a1v + F[q].z; t = fmaxf(t, ALPHA * t); p[q * 4 + 2] = A[q].z > 0 ? t : NEG_BIG;
            t = a1v + F[q].w; t = fmaxf(t, ALPHA * t); p[q * 4 + 3] = A[q].w > 0 ? t : NEG_BIG;
        }

        // row max: in-lane tree, then 2 shuffles across the 4 jc copies
        float u[16];
#pragma unroll
        for (int q = 0; q < 16; ++q) u[q] = fmaxf(p[q], p[q + 16]);
#pragma unroll
        for (int q = 0; q < 8; ++q) u[q] = fmaxf(u[q], u[q + 8]);
#pragma unroll
        for (int q = 0; q < 4; ++q) u[q] = fmaxf(u[q], u[q + 4]);
        float tm = fmaxf(fmaxf(u[0], u[1]), fmaxf(u[2], u[3]));
        tm = fmaxf(tm, __shfl_xor(tm, 16));
        tm = fmaxf(tm, __shfl_xor(tm, 32));

        const float m_new = fmaxf(m, tm);
        const float sc = exp2f(m - m_new);
        m = m_new;

#pragma unroll
        for (int q = 0; q < 32; ++q) p[q] = exp2f(p[q] - m_new);

        float v[16];
#pragma unroll
        for (int q = 0; q < 16; ++q) v[q] = p[q] + p[q + 16];
#pragma unroll
        for (int q = 0; q < 8; ++q) v[q] = v[q] + v[q + 8];
#pragma unroll
        for (int q = 0; q < 4; ++q) v[q] = v[q] + v[q + 4];
        float ps = (v[0] + v[1]) + (v[2] + v[3]);
        ps += __shfl_xor(ps, 16);
        ps += __shfl_xor(ps, 32);
        l = l * sc + ps;

        // pack P -> B-fragments (bf16)
        short8 Pb[4];
#pragma unroll
        for (int ks = 0; ks < 4; ++ks) {
            int4 wd;
            wd.x = (int)cvtpk_bf16(p[ks * 8 + 0], p[ks * 8 + 1]);
            wd.y = (int)cvtpk_bf16(p[ks * 8 + 2], p[ks * 8 + 3]);
            wd.z = (int)cvtpk_bf16(p[ks * 8 + 4], p[ks * 8 + 5]);
            wd.w = (int)cvtpk_bf16(p[ks * 8 + 6], p[ks * 8 + 7]);
            Pb[ks] = *(short8*)&wd;
        }

#pragma unroll
        for (int cb = 0; cb < 4; ++cb) {
            acc[cb][0] *= sc; acc[cb][1] *= sc; acc[cb][2] *= sc; acc[cb][3] *= sc;
        }
        __builtin_amdgcn_s_setprio(1);
#pragma unroll
        for (int ks = 0; ks < 4; ++ks) {
            acc[0] = __builtin_amdgcn_mfma_f32_16x16x32_bf16(h0[ks], Pb[ks], acc[0], 0, 0, 0);
            acc[1] = __builtin_amdgcn_mfma_f32_16x16x32_bf16(h1[ks], Pb[ks], acc[1], 0, 0, 0);
            acc[2] = __builtin_amdgcn_mfma_f32_16x16x32_bf16(h2[ks], Pb[ks], acc[2], 0, 0, 0);
            acc[3] = __builtin_amdgcn_mfma_f32_16x16x32_bf16(h3[ks], Pb[ks], acc[3], 0, 0, 0);
        }
        __builtin_amdgcn_s_setprio(0);

#pragma unroll
        for (int q = 0; q < 8; ++q) A[q] = An[q];
    }

    // ---- write chunk partials to LDS ----
#pragma unroll
    for (int cb = 0; cb < 4; ++cb)
        *(float4*)&accLds[sp][r][wv * 64 + cb * 16 + jc * 4] = *(float4*)&acc[cb];
    if (wv == 0 && jc == 0) { mlm[sp][r] = m; mll[sp][r] = l; }
    __syncthreads();

    // ---- log-sum-exp merge across the 4 chunks ----
    // thread t -> row r2 = t>>5, c-quad cq = t&31 (contiguous LDS/global)
    {
        const int r2 = tid >> 5, cq = tid & 31, c0 = cq * 4;
        float m0 = mlm[0][r2], m1 = mlm[1][r2], m2 = mlm[2][r2], m3 = mlm[3][r2];
        float M = fmaxf(fmaxf(m0, m1), fmaxf(m2, m3));
        float w0 = exp2f(m0 - M), w1 = exp2f(m1 - M);
        float w2 = exp2f(m2 - M), w3 = exp2f(m3 - M);
        float lt = w0 * mll[0][r2] + w1 * mll[1][r2] +
                   w2 * mll[2][r2] + w3 * mll[3][r2];
        float4 o0 = *(const float4*)&accLds[0][r2][c0];
        float4 o1 = *(const float4*)&accLds[1][r2][c0];
        float4 o2 = *(const float4*)&accLds[2][r2][c0];
        float4 o3 = *(const float4*)&accLds[3][r2][c0];
        const float inv = 1.f / lt;
        float4 bv = *(const float4*)&bias[c0];
        float4 o;
        o.x = (w0 * o0.x + w1 * o1.x + w2 * o2.x + w3 * o3.x) * inv + bv.x;
        o.y = (w0 * o0.y + w1 * o1.y + w2 * o2.y + w3 * o3.y) * inv + bv.y;
        o.z = (w0 * o0.z + w1 * o1.z + w2 * o2.z + w3 * o3.z) * inv + bv.z;
        o.w = (w0 * o0.w + w1 * o1.w + w2 * o2.w + w3 * o3.w) * inv + bv.w;
        *(float4*)(out + ((size_t)(b * N_ + i0 + r2)) * C_ + c0) = o;
    }
}

extern "C" void kernel_launch(void* const* d_in, const int* in_sizes, int n_in,
                              void* d_out, int out_size, void* d_ws, size_t ws_size,
                              hipStream_t stream) {
    const float* x    = (const float*)d_in[0];
    const int*   adj  = (const int*)d_in[1];
    const float* W    = (const float*)d_in[2];
    const float* a    = (const float*)d_in[3];
    const float* bias = (const float*)d_in[4];
    float* out = (float*)d_out;

    char* ws = (char*)d_ws;
    unsigned short* hT = (unsigned short*)ws;                        // 4 MB bf16 [B,C,N]
    float* at1 = (float*)(ws + (size_t)4 * 1024 * 1024);             // 64 KB
    float* at2 = (float*)(ws + (size_t)4 * 1024 * 1024 + 64 * 1024); // 64 KB

    k1_hidden<<<(B_ * N_) / 64, 256, 0, stream>>>(x, W, a, hT, at1, at2);
    k2_attn<<<B_ * (N_ / 16), 512, 0, stream>>>(adj, hT, at1, at2, bias, out);
}

// Round 10
// 113.753 us; speedup vs baseline: 1.1393x; 1.1393x over previous
//
#include <hip/hip_runtime.h>
#include <hip/hip_bf16.h>

#define ALPHA 0.2f
#define NEG_BIG -1e12f
#define LOG2E 1.44269504088896340736f

constexpr int B_ = 8, N_ = 2048, C_ = 128;
constexpr int JB = 128, NJT = N_ / JB;   // 16 j-tiles of 128

typedef __attribute__((ext_vector_type(8))) short short8;
typedef __attribute__((ext_vector_type(8))) unsigned short ushort8;
typedef __attribute__((ext_vector_type(4))) float f32x4;

__device__ __forceinline__ unsigned short f2bf(float f) {
    unsigned int u = __float_as_uint(f);
    u += 0x7fffu + ((u >> 16) & 1u);
    return (unsigned short)(u >> 16);
}

__device__ __forceinline__ unsigned int cvtpk_bf16(float lo, float hi) {
    unsigned int r;
    asm("v_cvt_pk_bf16_f32 %0, %1, %2" : "=v"(r) : "v"(lo), "v"(hi));
    return r;
}

// ---------------------------------------------------------------------------
// Kernel 1: hidden = x @ W (f32, exact), emit hiddenT bf16 [B, C, N] and
// attn1/attn2 = (hidden @ a) * LOG2E  (log2-domain logits for exp2 softmax).
// ---------------------------------------------------------------------------
__global__ __launch_bounds__(256) void k1_hidden(
    const float* __restrict__ x, const float* __restrict__ W,
    const float* __restrict__ a, unsigned short* __restrict__ hT,
    float* __restrict__ at1, float* __restrict__ at2)
{
    __shared__ float xs[64][C_];   // 32 KB
    __shared__ float Ws[C_][C_];   // 64 KB
    const int tid = threadIdx.x;
    const int row0 = blockIdx.x * 64;   // global row = b*N + n

    {
        const float4* xsrc = (const float4*)(x + (size_t)row0 * C_);
        float4* xdst = (float4*)&xs[0][0];
        for (int i = tid; i < 64 * C_ / 4; i += 256) xdst[i] = xsrc[i];
        const float4* wsrc = (const float4*)W;
        float4* wdst = (float4*)&Ws[0][0];
        for (int i = tid; i < C_ * C_ / 4; i += 256) wdst[i] = wsrc[i];
    }
    __syncthreads();

    const int tr = tid >> 5, tc = tid & 31;
    const int r0 = tr * 8, c0 = tc * 4;

    float acc[8][4];
#pragma unroll
    for (int i = 0; i < 8; ++i)
#pragma unroll
        for (int j = 0; j < 4; ++j) acc[i][j] = 0.f;

    for (int k = 0; k < C_; k += 4) {
        float4 w0 = *(const float4*)&Ws[k + 0][c0];
        float4 w1 = *(const float4*)&Ws[k + 1][c0];
        float4 w2 = *(const float4*)&Ws[k + 2][c0];
        float4 w3 = *(const float4*)&Ws[k + 3][c0];
#pragma unroll
        for (int rr = 0; rr < 8; ++rr) {
            float4 xv = *(const float4*)&xs[r0 + rr][k];
            acc[rr][0] += xv.x * w0.x + xv.y * w1.x + xv.z * w2.x + xv.w * w3.x;
            acc[rr][1] += xv.x * w0.y + xv.y * w1.y + xv.z * w2.y + xv.w * w3.y;
            acc[rr][2] += xv.x * w0.z + xv.y * w1.z + xv.z * w2.z + xv.w * w3.z;
            acc[rr][3] += xv.x * w0.w + xv.y * w1.w + xv.z * w2.w + xv.w * w3.w;
        }
    }

    float av0[4], av1[4];
#pragma unroll
    for (int cc = 0; cc < 4; ++cc) {
        av0[cc] = a[(c0 + cc) * 2 + 0];
        av1[cc] = a[(c0 + cc) * 2 + 1];
    }
#pragma unroll
    for (int rr = 0; rr < 8; ++rr) {
        float s1 = acc[rr][0] * av0[0] + acc[rr][1] * av0[1] +
                   acc[rr][2] * av0[2] + acc[rr][3] * av0[3];
        float s2 = acc[rr][0] * av1[0] + acc[rr][1] * av1[1] +
                   acc[rr][2] * av1[2] + acc[rr][3] * av1[3];
#pragma unroll
        for (int off = 1; off < 32; off <<= 1) {
            s1 += __shfl_xor(s1, off);
            s2 += __shfl_xor(s2, off);
        }
        if (tc == 0) {
            at1[row0 + r0 + rr] = s1 * LOG2E;
            at2[row0 + r0 + rr] = s2 * LOG2E;
        }
    }

    const int b = row0 >> 11;
    const int n0 = row0 & (N_ - 1);
#pragma unroll
    for (int cc = 0; cc < 4; ++cc) {
        ushort8 hv;
#pragma unroll
        for (int rr = 0; rr < 8; ++rr) hv[rr] = f2bf(acc[rr][cc]);
        *(ushort8*)(hT + ((size_t)b * C_ + c0 + cc) * N_ + n0 + r0) = hv;
    }
}

// ---------------------------------------------------------------------------
// Kernel 2: online-softmax flash attention with L1-shared loads.
// Block = 512 threads = 8 waves = (rg: 4 row-groups of 16 i-rows) x
// (wv: 2 c-halves).  Grid = 256 blocks.  The 4 rg-waves read IDENTICAL hT
// addresses and the 2 wv-waves IDENTICAL adj addresses -> L1 absorbs the
// duplication; a raw s_barrier per tile keeps waves phase-locked so the L1
// sharing holds.  Unique fabric traffic: adj 134 MB + hT 128 MB.
//
// Lane (r=lane&15, jc=lane>>4) owns row i=i0+rg*16+r, j = jt*128 + ks*32 +
// jc*8 + e (the MFMA B-fragment layout).  Swapped MFMA (A=hT, B=P):
// C/D col = r (i-row), row = jc*4+reg (c-local).  Online max needs only the
// 2 max-shuffles per tile; l stays lane-local (rescaled), reduced at the end.
// ---------------------------------------------------------------------------
__global__ __launch_bounds__(512, 2) void k2_attn(
    const int* __restrict__ adj, const unsigned short* __restrict__ hT,
    const float* __restrict__ at1, const float* __restrict__ at2,
    const float* __restrict__ bias, float* __restrict__ out)
{
    __shared__ float at2s[N_];    // 8 KB (log2-domain a2 for this batch)

    const int tid = threadIdx.x;
    const int b  = blockIdx.x >> 5;               // 32 i-groups of 64 per batch
    const int i0 = (blockIdx.x & 31) * 64;

    const int lane = tid & 63;
    const int w   = tid >> 6;                     // 0..7
    const int rg  = w >> 1;                       // row-group 0..3
    const int wv  = w & 1;                        // c-half 0/1
    const int r   = lane & 15;
    const int jc  = lane >> 4;

    // stage at2[b,:] into LDS (512 threads x 16B = 8 KB)
    ((float4*)at2s)[tid] = ((const float4*)(at2 + (size_t)b * N_))[tid];

    const int i = i0 + rg * 16 + r;
    const float a1v = at1[(size_t)b * N_ + i];

    const int* arow = adj + ((size_t)(b * N_ + i)) * N_ + jc * 8;
    const unsigned short* hrow =
        hT + ((size_t)b * C_ + wv * 64 + r) * N_ + jc * 8;

    f32x4 acc[4];
#pragma unroll
    for (int cb = 0; cb < 4; ++cb) acc[cb] = (f32x4){0.f, 0.f, 0.f, 0.f};
    float l0 = 0.f, l1 = 0.f, l2 = 0.f, l3 = 0.f;
    float m = -3e38f;

    // adj prefetch for jt=0: A[q], q = ks*2+h -> j = ks*32 + jc*8 + h*4 + e
    int4 A[8];
#pragma unroll
    for (int q = 0; q < 8; ++q)
        A[q] = *(const int4*)(arow + (q >> 1) * 32 + (q & 1) * 4);

    __syncthreads();   // at2s visible

#pragma unroll 2
    for (int jt = 0; jt < NJT; ++jt) {
        // phase-lock the 8 waves so rg/wv-duplicate loads hit L1.
        // raw s_barrier: no waitcnt semantics, prefetches stay in flight.
        __builtin_amdgcn_s_barrier();

        const int j0 = jt * JB;

        // hT A-fragments (consumed by MFMA at the end of the body)
        short8 h0[4], h1[4], h2[4], h3[4];
#pragma unroll
        for (int ks = 0; ks < 4; ++ks) {
            h0[ks] = *(const short8*)(hrow + j0 + ks * 32);
            h1[ks] = *(const short8*)(hrow + (size_t)16 * N_ + j0 + ks * 32);
            h2[ks] = *(const short8*)(hrow + (size_t)32 * N_ + j0 + ks * 32);
            h3[ks] = *(const short8*)(hrow + (size_t)48 * N_ + j0 + ks * 32);
        }

        // next-tile adj prefetch (register-renamed by unroll; never drained)
        const int jn = (jt + 1 < NJT ? jt + 1 : jt) * JB;
        int4 An[8];
#pragma unroll
        for (int q = 0; q < 8; ++q)
            An[q] = *(const int4*)(arow + jn + (q >> 1) * 32 + (q & 1) * 4);

        // at2 for this tile from LDS (log2 domain)
        float4 F[8];
#pragma unroll
        for (int q = 0; q < 8; ++q)
            F[q] = *(const float4*)&at2s[j0 + (q >> 1) * 32 + jc * 8 + (q & 1) * 4];

        // logits (log2 domain): leaky commutes with positive scale
        float p[32];
#pragma unroll
        for (int q = 0; q < 8; ++q) {
            float t;
            t = a1v + F[q].x; t = fmaxf(t, ALPHA * t); p[q * 4 + 0] = A[q].x > 0 ? t : NEG_BIG;
            t = a1v + F[q].y; t = fmaxf(t, ALPHA * t); p[q * 4 + 1] = A[q].y > 0 ? t : NEG_BIG;
            t = a1v + F[q].z; t = fmaxf(t, ALPHA * t); p[q * 4 + 2] = A[q].z > 0 ? t : NEG_BIG;
            t = a1v + F[q].w; t = fmaxf(t, ALPHA * t); p[q * 4 + 3] = A[q].w > 0 ? t : NEG_BIG;
        }

        // row max: in-lane tree, then 2 shuffles across the 4 jc copies
        float u[16];
#pragma unroll
        for (int q = 0; q < 16; ++q) u[q] = fmaxf(p[q], p[q + 16]);
#pragma unroll
        for (int q = 0; q < 8; ++q) u[q] = fmaxf(u[q], u[q + 8]);
#pragma unroll
        for (int q = 0; q < 4; ++q) u[q] = fmaxf(u[q], u[q + 4]);
        float tm = fmaxf(fmaxf(u[0], u[1]), fmaxf(u[2], u[3]));
        tm = fmaxf(tm, __shfl_xor(tm, 16));
        tm = fmaxf(tm, __shfl_xor(tm, 32));

        const float m_new = fmaxf(m, tm);
        const float sc = exp2f(m - m_new);
        m = m_new;

#pragma unroll
        for (int q = 0; q < 32; ++q) p[q] = exp2f(p[q] - m_new);

        // lane-local denominator with rescale (no cross-lane reduce per tile)
        float s0 = 0.f, s1 = 0.f, s2 = 0.f, s3 = 0.f;
#pragma unroll
        for (int q = 0; q < 8; ++q) {
            s0 += p[q * 4 + 0];
            s1 += p[q * 4 + 1];
            s2 += p[q * 4 + 2];
            s3 += p[q * 4 + 3];
        }
        l0 = l0 * sc + s0;
        l1 = l1 * sc + s1;
        l2 = l2 * sc + s2;
        l3 = l3 * sc + s3;

        // pack P -> B-fragments (bf16)
        short8 Pb[4];
#pragma unroll
        for (int ks = 0; ks < 4; ++ks) {
            int4 wd;
            wd.x = (int)cvtpk_bf16(p[ks * 8 + 0], p[ks * 8 + 1]);
            wd.y = (int)cvtpk_bf16(p[ks * 8 + 2], p[ks * 8 + 3]);
            wd.z = (int)cvtpk_bf16(p[ks * 8 + 4], p[ks * 8 + 5]);
            wd.w = (int)cvtpk_bf16(p[ks * 8 + 6], p[ks * 8 + 7]);
            Pb[ks] = *(short8*)&wd;
        }

        // rescale acc, then MFMA
#pragma unroll
        for (int cb = 0; cb < 4; ++cb) {
            acc[cb][0] *= sc; acc[cb][1] *= sc; acc[cb][2] *= sc; acc[cb][3] *= sc;
        }
        __builtin_amdgcn_s_setprio(1);
#pragma unroll
        for (int ks = 0; ks < 4; ++ks) {
            acc[0] = __builtin_amdgcn_mfma_f32_16x16x32_bf16(h0[ks], Pb[ks], acc[0], 0, 0, 0);
            acc[1] = __builtin_amdgcn_mfma_f32_16x16x32_bf16(h1[ks], Pb[ks], acc[1], 0, 0, 0);
            acc[2] = __builtin_amdgcn_mfma_f32_16x16x32_bf16(h2[ks], Pb[ks], acc[2], 0, 0, 0);
            acc[3] = __builtin_amdgcn_mfma_f32_16x16x32_bf16(h3[ks], Pb[ks], acc[3], 0, 0, 0);
        }
        __builtin_amdgcn_s_setprio(0);

#pragma unroll
        for (int q = 0; q < 8; ++q) A[q] = An[q];
    }

    // ---- epilogue: one reduce for l, then out = acc/l + bias ----
    float lt = (l0 + l1) + (l2 + l3);
    lt += __shfl_xor(lt, 16);
    lt += __shfl_xor(lt, 32);
    const float invl = 1.f / lt;

#pragma unroll
    for (int cb = 0; cb < 4; ++cb) {
        const int c0 = wv * 64 + cb * 16 + jc * 4;
        float4 bv = *(const float4*)&bias[c0];
        float4 o;
        o.x = acc[cb][0] * invl + bv.x;
        o.y = acc[cb][1] * invl + bv.y;
        o.z = acc[cb][2] * invl + bv.z;
        o.w = acc[cb][3] * invl + bv.w;
        *(float4*)(out + ((size_t)(b * N_ + i)) * C_ + c0) = o;
    }
}

extern "C" void kernel_launch(void* const* d_in, const int* in_sizes, int n_in,
                              void* d_out, int out_size, void* d_ws, size_t ws_size,
                              hipStream_t stream) {
    const float* x    = (const float*)d_in[0];
    const int*   adj  = (const int*)d_in[1];
    const float* W    = (const float*)d_in[2];
    const float* a    = (const float*)d_in[3];
    const float* bias = (const float*)d_in[4];
    float* out = (float*)d_out;

    char* ws = (char*)d_ws;
    unsigned short* hT = (unsigned short*)ws;                        // 4 MB bf16 [B,C,N]
    float* at1 = (float*)(ws + (size_t)4 * 1024 * 1024);             // 64 KB
    float* at2 = (float*)(ws + (size_t)4 * 1024 * 1024 + 64 * 1024); // 64 KB

    k1_hidden<<<(B_ * N_) / 64, 256, 0, stream>>>(x, W, a, hT, at1, at2);
    k2_attn<<<B_ * (N_ / 64), 512, 0, stream>>>(adj, hT, at1, at2, bias, out);
}

// Round 11
// 106.599 us; speedup vs baseline: 1.2157x; 1.0671x over previous
//
#include <hip/hip_runtime.h>
#include <hip/hip_bf16.h>

#define ALPHA 0.2f
#define NEG_BIG -1e12f
#define LOG2E 1.44269504088896340736f

constexpr int B_ = 8, N_ = 2048, C_ = 128;
constexpr int IB = 16, JB = 128, NJT = N_ / JB;   // 16 j-tiles

typedef __attribute__((ext_vector_type(8))) short short8;
typedef __attribute__((ext_vector_type(8))) unsigned short ushort8;
typedef __attribute__((ext_vector_type(4))) float f32x4;

__device__ __forceinline__ unsigned short f2bf(float f) {
    unsigned int u = __float_as_uint(f);
    u += 0x7fffu + ((u >> 16) & 1u);
    return (unsigned short)(u >> 16);
}

__device__ __forceinline__ unsigned int cvtpk_bf16(float lo, float hi) {
    unsigned int r;
    asm("v_cvt_pk_bf16_f32 %0, %1, %2" : "=v"(r) : "v"(lo), "v"(hi));
    return r;
}

// lgkm-only barrier (global prefetches stay in flight)
__device__ __forceinline__ void barrier_lds_only() {
    asm volatile("s_waitcnt lgkmcnt(0)" ::: "memory");
    __builtin_amdgcn_s_barrier();
}

// ---------------------------------------------------------------------------
// Pack kernel: adj int32 {0,1} [B,N,N] -> 1-bit mask [B*N*N/32] u32.
// The unavoidable 134 MB HBM read happens HERE, perfectly streamed; k2 then
// reads a 4.2 MB L2-resident bitmask instead (32x traffic + line-count cut).
// Each thread packs 32 consecutive ints (128 B contiguous).
// ---------------------------------------------------------------------------
__global__ __launch_bounds__(256) void k_pack(
    const int* __restrict__ adj, unsigned int* __restrict__ abits)
{
    const size_t w = (size_t)blockIdx.x * 256 + threadIdx.x;   // word index
    const int4* src = (const int4*)adj + w * 8;
    int4 v[8];
#pragma unroll
    for (int q = 0; q < 8; ++q) v[q] = src[q];
    unsigned int m = 0;
#pragma unroll
    for (int q = 0; q < 8; ++q) {
        m |= (v[q].x > 0 ? 1u : 0u) << (q * 4 + 0);
        m |= (v[q].y > 0 ? 1u : 0u) << (q * 4 + 1);
        m |= (v[q].z > 0 ? 1u : 0u) << (q * 4 + 2);
        m |= (v[q].w > 0 ? 1u : 0u) << (q * 4 + 3);
    }
    abits[w] = m;
}

// ---------------------------------------------------------------------------
// Kernel 1: hidden = x @ W (f32, exact), emit hiddenT bf16 [B, C, N] and
// attn1/attn2 = (hidden @ a) * LOG2E  (log2-domain logits for exp2 softmax).
// ---------------------------------------------------------------------------
__global__ __launch_bounds__(256) void k1_hidden(
    const float* __restrict__ x, const float* __restrict__ W,
    const float* __restrict__ a, unsigned short* __restrict__ hT,
    float* __restrict__ at1, float* __restrict__ at2)
{
    __shared__ float xs[64][C_];   // 32 KB
    __shared__ float Ws[C_][C_];   // 64 KB
    const int tid = threadIdx.x;
    const int row0 = blockIdx.x * 64;   // global row = b*N + n

    {
        const float4* xsrc = (const float4*)(x + (size_t)row0 * C_);
        float4* xdst = (float4*)&xs[0][0];
        for (int i = tid; i < 64 * C_ / 4; i += 256) xdst[i] = xsrc[i];
        const float4* wsrc = (const float4*)W;
        float4* wdst = (float4*)&Ws[0][0];
        for (int i = tid; i < C_ * C_ / 4; i += 256) wdst[i] = wsrc[i];
    }
    __syncthreads();

    const int tr = tid >> 5, tc = tid & 31;
    const int r0 = tr * 8, c0 = tc * 4;

    float acc[8][4];
#pragma unroll
    for (int i = 0; i < 8; ++i)
#pragma unroll
        for (int j = 0; j < 4; ++j) acc[i][j] = 0.f;

    for (int k = 0; k < C_; k += 4) {
        float4 w0 = *(const float4*)&Ws[k + 0][c0];
        float4 w1 = *(const float4*)&Ws[k + 1][c0];
        float4 w2 = *(const float4*)&Ws[k + 2][c0];
        float4 w3 = *(const float4*)&Ws[k + 3][c0];
#pragma unroll
        for (int rr = 0; rr < 8; ++rr) {
            float4 xv = *(const float4*)&xs[r0 + rr][k];
            acc[rr][0] += xv.x * w0.x + xv.y * w1.x + xv.z * w2.x + xv.w * w3.x;
            acc[rr][1] += xv.x * w0.y + xv.y * w1.y + xv.z * w2.y + xv.w * w3.y;
            acc[rr][2] += xv.x * w0.z + xv.y * w1.z + xv.z * w2.z + xv.w * w3.z;
            acc[rr][3] += xv.x * w0.w + xv.y * w1.w + xv.z * w2.w + xv.w * w3.w;
        }
    }

    float av0[4], av1[4];
#pragma unroll
    for (int cc = 0; cc < 4; ++cc) {
        av0[cc] = a[(c0 + cc) * 2 + 0];
        av1[cc] = a[(c0 + cc) * 2 + 1];
    }
#pragma unroll
    for (int rr = 0; rr < 8; ++rr) {
        float s1 = acc[rr][0] * av0[0] + acc[rr][1] * av0[1] +
                   acc[rr][2] * av0[2] + acc[rr][3] * av0[3];
        float s2 = acc[rr][0] * av1[0] + acc[rr][1] * av1[1] +
                   acc[rr][2] * av1[2] + acc[rr][3] * av1[3];
#pragma unroll
        for (int off = 1; off < 32; off <<= 1) {
            s1 += __shfl_xor(s1, off);
            s2 += __shfl_xor(s2, off);
        }
        if (tc == 0) {
            at1[row0 + r0 + rr] = s1 * LOG2E;
            at2[row0 + r0 + rr] = s2 * LOG2E;
        }
    }

    const int b = row0 >> 11;
    const int n0 = row0 & (N_ - 1);
#pragma unroll
    for (int cc = 0; cc < 4; ++cc) {
        ushort8 hv;
#pragma unroll
        for (int rr = 0; rr < 8; ++rr) hv[rr] = f2bf(acc[rr][cc]);
        *(ushort8*)(hT + ((size_t)b * C_ + c0 + cc) * N_ + n0 + r0) = hv;
    }
}

// ---------------------------------------------------------------------------
// Kernel 2: R3 structure (79 us best), adj path replaced by the bitmask.
// IB=16 rows/block, JB=128 j-tile, 256 threads (4 waves, c-split 32 each).
// Double-buffered P + srow -> ONE lgkm-only barrier per tile.
// Mask: one u32 load per thread per tile (L1-resident, 4 KB/block footprint)
// instead of 8 scattered int4 loads from the 134 MB adj.
// ---------------------------------------------------------------------------
__global__ __launch_bounds__(256, 4) void k2_attn(
    const unsigned int* __restrict__ abits, const unsigned short* __restrict__ hT,
    const float* __restrict__ at1, const float* __restrict__ at2,
    const float* __restrict__ bias, float* __restrict__ out)
{
    __shared__ unsigned short P[2][IB][JB + 8];   // 2 x 16 x 136 bf16 (8.7 KB)
    __shared__ float at2s[N_];                    // 8 KB
    __shared__ float mrow[IB], lrow[IB], srow[2][IB];

    const int tid = threadIdx.x;
    const int b  = blockIdx.x >> 7;               // 128 i-tiles per batch
    const int i0 = (blockIdx.x & 127) * IB;

    {
        const float4* src = (const float4*)(at2 + (size_t)b * N_);
        float4* dst = (float4*)at2s;
        dst[tid]       = src[tid];
        dst[tid + 256] = src[tid + 256];
    }
    if (tid < IB) { mrow[tid] = -3e38f; lrow[tid] = 0.f; }

    // softmax-side ids: 16 threads per row, 8 j each
    const int r  = tid >> 4;                      // 0..15
    const int jl = tid & 15;                      // 0..15
    const float a1v = at1[(size_t)b * N_ + i0 + r];
    // word for j = jt*128 + jl*8 + e : index jt*4 + (jl>>2), bits (jl&3)*8+e
    const unsigned int* abrow =
        abits + ((size_t)(b * N_ + i0 + r)) * (N_ / 32) + (jl >> 2);
    const int sh = (jl & 3) * 8;

    // MFMA-side ids
    const int lane = tid & 63;
    const int wv = tid >> 6;                      // wave 0..3 -> 32-col slice
    const int lg = lane >> 4;                     // 0..3
    const int ll = lane & 15;
    const unsigned short* hb = hT + ((size_t)b * C_ + wv * 32 + ll) * N_;

    f32x4 acc0 = {0.f, 0.f, 0.f, 0.f}, acc1 = {0.f, 0.f, 0.f, 0.f};

    __syncthreads();   // at2s + mrow/lrow init visible

    for (int jt = 0; jt < NJT; ++jt) {
        const int buf = jt & 1;

        // mask word for this tile (tiny, L1-hit after jt=0)
        const unsigned int wbits = abrow[jt * 4] >> sh;

        // hT B-fragment loads for THIS tile (consumed after barrier)
        short8 vb0[4], vb1[4];
        {
            const unsigned short* hrow = hb + jt * JB + lg * 8;
#pragma unroll
            for (int ks = 0; ks < 4; ++ks) {
                vb0[ks] = *(const short8*)(hrow + ks * 32);
                vb1[ks] = *(const short8*)(hrow + (size_t)16 * N_ + ks * 32);
            }
        }

        float4 f0 = *(const float4*)&at2s[jt * JB + jl * 8];
        float4 f1 = *(const float4*)&at2s[jt * JB + jl * 8 + 4];

        // logits (log2 domain): leaky commutes with positive scale
        float s[8];
        {
            float t;
            t = a1v + f0.x; t = fmaxf(t, ALPHA * t); s[0] = (wbits & 1u)   ? t : NEG_BIG;
            t = a1v + f0.y; t = fmaxf(t, ALPHA * t); s[1] = (wbits & 2u)   ? t : NEG_BIG;
            t = a1v + f0.z; t = fmaxf(t, ALPHA * t); s[2] = (wbits & 4u)   ? t : NEG_BIG;
            t = a1v + f0.w; t = fmaxf(t, ALPHA * t); s[3] = (wbits & 8u)   ? t : NEG_BIG;
            t = a1v + f1.x; t = fmaxf(t, ALPHA * t); s[4] = (wbits & 16u)  ? t : NEG_BIG;
            t = a1v + f1.y; t = fmaxf(t, ALPHA * t); s[5] = (wbits & 32u)  ? t : NEG_BIG;
            t = a1v + f1.z; t = fmaxf(t, ALPHA * t); s[6] = (wbits & 64u)  ? t : NEG_BIG;
            t = a1v + f1.w; t = fmaxf(t, ALPHA * t); s[7] = (wbits & 128u) ? t : NEG_BIG;
        }
        float tm = fmaxf(fmaxf(fmaxf(s[0], s[1]), fmaxf(s[2], s[3])),
                         fmaxf(fmaxf(s[4], s[5]), fmaxf(s[6], s[7])));
        tm = fmaxf(tm, __shfl_xor(tm, 1));
        tm = fmaxf(tm, __shfl_xor(tm, 2));
        tm = fmaxf(tm, __shfl_xor(tm, 4));
        tm = fmaxf(tm, __shfl_xor(tm, 8));

        const float m_old = mrow[r];           // lockstep within wave
        const float m_new = fmaxf(m_old, tm);

        float p[8];
        float ps = 0.f;
#pragma unroll
        for (int e = 0; e < 8; ++e) { p[e] = exp2f(s[e] - m_new); ps += p[e]; }
        ps += __shfl_xor(ps, 1);
        ps += __shfl_xor(ps, 2);
        ps += __shfl_xor(ps, 4);
        ps += __shfl_xor(ps, 8);

        int4 pw;
        pw.x = (int)cvtpk_bf16(p[0], p[1]);
        pw.y = (int)cvtpk_bf16(p[2], p[3]);
        pw.z = (int)cvtpk_bf16(p[4], p[5]);
        pw.w = (int)cvtpk_bf16(p[6], p[7]);
        *(int4*)&P[buf][r][jl * 8] = pw;

        if (jl == 0) {
            const float sc = exp2f(m_old - m_new);
            srow[buf][r] = sc;
            mrow[r] = m_new;
            lrow[r] = lrow[r] * sc + ps;
        }
        barrier_lds_only();   // P[buf], srow[buf] ready; protects buf at jt+2

        // ---- MFMA phase: this wave does 16(i) x 32(c) x 128(j) ----
        const char* Pb = (const char*)P[buf];
        short8 pa[4];
#pragma unroll
        for (int ks = 0; ks < 4; ++ks)
            pa[ks] = *(const short8*)(Pb + ll * 272 + ks * 64 + lg * 16);

        float4 sc4 = *(const float4*)&srow[buf][lg * 4];
        acc0[0] *= sc4.x; acc0[1] *= sc4.y; acc0[2] *= sc4.z; acc0[3] *= sc4.w;
        acc1[0] *= sc4.x; acc1[1] *= sc4.y; acc1[2] *= sc4.z; acc1[3] *= sc4.w;

        __builtin_amdgcn_s_setprio(1);
#pragma unroll
        for (int ks = 0; ks < 4; ++ks) {
            acc0 = __builtin_amdgcn_mfma_f32_16x16x32_bf16(pa[ks], vb0[ks], acc0, 0, 0, 0);
            acc1 = __builtin_amdgcn_mfma_f32_16x16x32_bf16(pa[ks], vb1[ks], acc1, 0, 0, 0);
        }
        __builtin_amdgcn_s_setprio(0);
    }

    // ---- epilogue: out = acc / l + bias ----
    float4 lw = *(const float4*)&lrow[lg * 4];
    const int c = wv * 32 + ll;
    const float bv0 = bias[c];
    const float bv1 = bias[c + 16];

    float* o = out + ((size_t)(b * N_ + i0 + lg * 4)) * C_ + c;
    o[0 * C_]      = acc0[0] / lw.x + bv0;
    o[1 * C_]      = acc0[1] / lw.y + bv0;
    o[2 * C_]      = acc0[2] / lw.z + bv0;
    o[3 * C_]      = acc0[3] / lw.w + bv0;
    o[0 * C_ + 16] = acc1[0] / lw.x + bv1;
    o[1 * C_ + 16] = acc1[1] / lw.y + bv1;
    o[2 * C_ + 16] = acc1[2] / lw.z + bv1;
    o[3 * C_ + 16] = acc1[3] / lw.w + bv1;
}

extern "C" void kernel_launch(void* const* d_in, const int* in_sizes, int n_in,
                              void* d_out, int out_size, void* d_ws, size_t ws_size,
                              hipStream_t stream) {
    const float* x    = (const float*)d_in[0];
    const int*   adj  = (const int*)d_in[1];
    const float* W    = (const float*)d_in[2];
    const float* a    = (const float*)d_in[3];
    const float* bias = (const float*)d_in[4];
    float* out = (float*)d_out;

    char* ws = (char*)d_ws;
    unsigned int*   abits = (unsigned int*)ws;                        // 4 MB bitmask
    unsigned short* hT  = (unsigned short*)(ws + (size_t)4 * 1024 * 1024);   // 4 MB
    float* at1 = (float*)(ws + (size_t)8 * 1024 * 1024);              // 64 KB
    float* at2 = (float*)(ws + (size_t)8 * 1024 * 1024 + 64 * 1024);  // 64 KB

    k_pack<<<(B_ * N_ * (N_ / 32)) / 256, 256, 0, stream>>>(adj, abits);
    k1_hidden<<<(B_ * N_) / 64, 256, 0, stream>>>(x, W, a, hT, at1, at2);
    k2_attn<<<B_ * (N_ / IB), 256, 0, stream>>>(abits, hT, at1, at2, bias, out);
}

// Round 12
// 89.190 us; speedup vs baseline: 1.4530x; 1.1952x over previous
//
#include <hip/hip_runtime.h>
#include <hip/hip_bf16.h>

#define ALPHA 0.2f
#define NEG_BIG -1e12f
#define LOG2E 1.44269504088896340736f

constexpr int B_ = 8, N_ = 2048, C_ = 128;
constexpr int IB = 32, JB = 128, NJT = N_ / JB;   // 16 j-tiles

typedef __attribute__((ext_vector_type(8))) short short8;
typedef __attribute__((ext_vector_type(8))) unsigned short ushort8;
typedef __attribute__((ext_vector_type(4))) float f32x4;

__device__ __forceinline__ unsigned short f2bf(float f) {
    unsigned int u = __float_as_uint(f);
    u += 0x7fffu + ((u >> 16) & 1u);
    return (unsigned short)(u >> 16);
}

__device__ __forceinline__ unsigned int cvtpk_bf16(float lo, float hi) {
    unsigned int r;
    asm("v_cvt_pk_bf16_f32 %0, %1, %2" : "=v"(r) : "v"(lo), "v"(hi));
    return r;
}

// lgkm-only barrier (global prefetches stay in flight across it)
__device__ __forceinline__ void barrier_lds_only() {
    asm volatile("s_waitcnt lgkmcnt(0)" ::: "memory");
    __builtin_amdgcn_s_barrier();
}

// ---------------------------------------------------------------------------
// Kernel 1: hidden = x @ W (f32, exact), emit hiddenT bf16 [B, C, N] and
// attn1/attn2 = (hidden @ a) * LOG2E  (log2-domain logits for exp2 softmax).
// ---------------------------------------------------------------------------
__global__ __launch_bounds__(256) void k1_hidden(
    const float* __restrict__ x, const float* __restrict__ W,
    const float* __restrict__ a, unsigned short* __restrict__ hT,
    float* __restrict__ at1, float* __restrict__ at2)
{
    __shared__ float xs[64][C_];   // 32 KB
    __shared__ float Ws[C_][C_];   // 64 KB
    const int tid = threadIdx.x;
    const int row0 = blockIdx.x * 64;   // global row = b*N + n

    {
        const float4* xsrc = (const float4*)(x + (size_t)row0 * C_);
        float4* xdst = (float4*)&xs[0][0];
        for (int i = tid; i < 64 * C_ / 4; i += 256) xdst[i] = xsrc[i];
        const float4* wsrc = (const float4*)W;
        float4* wdst = (float4*)&Ws[0][0];
        for (int i = tid; i < C_ * C_ / 4; i += 256) wdst[i] = wsrc[i];
    }
    __syncthreads();

    const int tr = tid >> 5, tc = tid & 31;
    const int r0 = tr * 8, c0 = tc * 4;

    float acc[8][4];
#pragma unroll
    for (int i = 0; i < 8; ++i)
#pragma unroll
        for (int j = 0; j < 4; ++j) acc[i][j] = 0.f;

    for (int k = 0; k < C_; k += 4) {
        float4 w0 = *(const float4*)&Ws[k + 0][c0];
        float4 w1 = *(const float4*)&Ws[k + 1][c0];
        float4 w2 = *(const float4*)&Ws[k + 2][c0];
        float4 w3 = *(const float4*)&Ws[k + 3][c0];
#pragma unroll
        for (int rr = 0; rr < 8; ++rr) {
            float4 xv = *(const float4*)&xs[r0 + rr][k];
            acc[rr][0] += xv.x * w0.x + xv.y * w1.x + xv.z * w2.x + xv.w * w3.x;
            acc[rr][1] += xv.x * w0.y + xv.y * w1.y + xv.z * w2.y + xv.w * w3.y;
            acc[rr][2] += xv.x * w0.z + xv.y * w1.z + xv.z * w2.z + xv.w * w3.z;
            acc[rr][3] += xv.x * w0.w + xv.y * w1.w + xv.z * w2.w + xv.w * w3.w;
        }
    }

    float av0[4], av1[4];
#pragma unroll
    for (int cc = 0; cc < 4; ++cc) {
        av0[cc] = a[(c0 + cc) * 2 + 0];
        av1[cc] = a[(c0 + cc) * 2 + 1];
    }
#pragma unroll
    for (int rr = 0; rr < 8; ++rr) {
        float s1 = acc[rr][0] * av0[0] + acc[rr][1] * av0[1] +
                   acc[rr][2] * av0[2] + acc[rr][3] * av0[3];
        float s2 = acc[rr][0] * av1[0] + acc[rr][1] * av1[1] +
                   acc[rr][2] * av1[2] + acc[rr][3] * av1[3];
#pragma unroll
        for (int off = 1; off < 32; off <<= 1) {
            s1 += __shfl_xor(s1, off);
            s2 += __shfl_xor(s2, off);
        }
        if (tc == 0) {
            at1[row0 + r0 + rr] = s1 * LOG2E;
            at2[row0 + r0 + rr] = s2 * LOG2E;
        }
    }

    const int b = row0 >> 11;
    const int n0 = row0 & (N_ - 1);
#pragma unroll
    for (int cc = 0; cc < 4; ++cc) {
        ushort8 hv;
#pragma unroll
        for (int rr = 0; rr < 8; ++rr) hv[rr] = f2bf(acc[rr][cc]);
        *(ushort8*)(hT + ((size_t)b * C_ + c0 + cc) * N_ + n0 + r0) = hv;
    }
}

// ---------------------------------------------------------------------------
// Kernel 2: R3 pipeline scaled to IB=32.
// 512 threads = 8 waves = (wv: 4 c-slices of 32) x (rh: 2 row-halves of 16).
// Grid = 512 blocks = exactly 2/CU -> 16 waves/CU = 4/SIMD (R3's TLP), but
// each block serves 2x the rows per hT tile read, and the rh-wave pairs issue
// IDENTICAL vb addresses (L1 dedup) -> hT/L1 traffic per output row ~4x lower.
// Double-buffered P + srow -> ONE lgkm-only barrier per tile; vmcnt never
// drains in the loop so adj/hT prefetches stay in flight.
// ---------------------------------------------------------------------------
__global__ __launch_bounds__(512, 2) void k2_attn(
    const int* __restrict__ adj, const unsigned short* __restrict__ hT,
    const float* __restrict__ at1, const float* __restrict__ at2,
    const float* __restrict__ bias, float* __restrict__ out)
{
    __shared__ unsigned short P[2][IB][JB + 8];   // 2 x 32 x 136 bf16 (17.4 KB)
    __shared__ float at2s[N_];                    // 8 KB
    __shared__ float mrow[IB], lrow[IB], srow[2][IB];

    const int tid = threadIdx.x;
    const int b  = blockIdx.x >> 6;               // 64 i-tiles per batch
    const int i0 = (blockIdx.x & 63) * IB;

    // stage at2[b,:] into LDS (512 threads x 16B = 8 KB)
    ((float4*)at2s)[tid] = ((const float4*)(at2 + (size_t)b * N_))[tid];
    if (tid < IB) { mrow[tid] = -3e38f; lrow[tid] = 0.f; }

    // softmax-side ids: 16 threads per row, 8 j each
    const int r  = tid >> 4;                      // 0..31
    const int jl = tid & 15;                      // 0..15
    const float a1v = at1[(size_t)b * N_ + i0 + r];
    const int* arow = adj + ((size_t)(b * N_ + i0 + r)) * N_ + jl * 8;

    // MFMA-side ids
    const int lane = tid & 63;
    const int w  = tid >> 6;                      // 0..7
    const int wv = w & 3;                         // c-slice (32 cols)
    const int rh = w >> 2;                        // row-half (16 rows)
    const int lg = lane >> 4;                     // 0..3
    const int ll = lane & 15;
    const unsigned short* hb = hT + ((size_t)b * C_ + wv * 32 + ll) * N_;

    f32x4 acc0 = {0.f, 0.f, 0.f, 0.f}, acc1 = {0.f, 0.f, 0.f, 0.f};

    __syncthreads();   // at2s + mrow/lrow init visible (once)

    int4 pf0 = *(const int4*)arow;
    int4 pf1 = *(const int4*)(arow + 4);

    for (int jt = 0; jt < NJT; ++jt) {
        const int buf = jt & 1;

        // hT B-fragment loads for THIS tile (consumed after barrier).
        // rh=0 and rh=1 waves of a c-slice issue identical addresses -> L1.
        short8 vb0[4], vb1[4];
        {
            const unsigned short* hrow = hb + jt * JB + lg * 8;
#pragma unroll
            for (int ks = 0; ks < 4; ++ks) {
                vb0[ks] = *(const short8*)(hrow + ks * 32);
                vb1[ks] = *(const short8*)(hrow + (size_t)16 * N_ + ks * 32);
            }
        }

        int4 A0 = pf0, A1 = pf1;
        if (jt + 1 < NJT) {
            pf0 = *(const int4*)(arow + (jt + 1) * JB);
            pf1 = *(const int4*)(arow + (jt + 1) * JB + 4);
        }
        float4 f0 = *(const float4*)&at2s[jt * JB + jl * 8];
        float4 f1 = *(const float4*)&at2s[jt * JB + jl * 8 + 4];

        // logits (log2 domain): leaky commutes with positive scale
        float s[8];
        {
            float t;
            t = a1v + f0.x; t = fmaxf(t, ALPHA * t); s[0] = A0.x > 0 ? t : NEG_BIG;
            t = a1v + f0.y; t = fmaxf(t, ALPHA * t); s[1] = A0.y > 0 ? t : NEG_BIG;
            t = a1v + f0.z; t = fmaxf(t, ALPHA * t); s[2] = A0.z > 0 ? t : NEG_BIG;
            t = a1v + f0.w; t = fmaxf(t, ALPHA * t); s[3] = A0.w > 0 ? t : NEG_BIG;
            t = a1v + f1.x; t = fmaxf(t, ALPHA * t); s[4] = A1.x > 0 ? t : NEG_BIG;
            t = a1v + f1.y; t = fmaxf(t, ALPHA * t); s[5] = A1.y > 0 ? t : NEG_BIG;
            t = a1v + f1.z; t = fmaxf(t, ALPHA * t); s[6] = A1.z > 0 ? t : NEG_BIG;
            t = a1v + f1.w; t = fmaxf(t, ALPHA * t); s[7] = A1.w > 0 ? t : NEG_BIG;
        }
        float tm = fmaxf(fmaxf(fmaxf(s[0], s[1]), fmaxf(s[2], s[3])),
                         fmaxf(fmaxf(s[4], s[5]), fmaxf(s[6], s[7])));
        tm = fmaxf(tm, __shfl_xor(tm, 1));
        tm = fmaxf(tm, __shfl_xor(tm, 2));
        tm = fmaxf(tm, __shfl_xor(tm, 4));
        tm = fmaxf(tm, __shfl_xor(tm, 8));

        const float m_old = mrow[r];           // row-threads are wave-lockstep
        const float m_new = fmaxf(m_old, tm);

        float p[8];
        float ps = 0.f;
#pragma unroll
        for (int e = 0; e < 8; ++e) { p[e] = exp2f(s[e] - m_new); ps += p[e]; }
        ps += __shfl_xor(ps, 1);
        ps += __shfl_xor(ps, 2);
        ps += __shfl_xor(ps, 4);
        ps += __shfl_xor(ps, 8);

        int4 pw;
        pw.x = (int)cvtpk_bf16(p[0], p[1]);
        pw.y = (int)cvtpk_bf16(p[2], p[3]);
        pw.z = (int)cvtpk_bf16(p[4], p[5]);
        pw.w = (int)cvtpk_bf16(p[6], p[7]);
        *(int4*)&P[buf][r][jl * 8] = pw;

        if (jl == 0) {
            const float sc = exp2f(m_old - m_new);
            srow[buf][r] = sc;
            mrow[r] = m_new;
            lrow[r] = lrow[r] * sc + ps;
        }
        barrier_lds_only();   // P[buf], srow[buf] ready; protects buf at jt+2

        // ---- MFMA phase: this wave does 16(i: rh half) x 32(c) x 128(j) ----
        const char* Pb = (const char*)P[buf];
        short8 pa[4];
#pragma unroll
        for (int ks = 0; ks < 4; ++ks)
            pa[ks] = *(const short8*)(Pb + (rh * 16 + ll) * 272 + ks * 64 + lg * 16);

        float4 sc4 = *(const float4*)&srow[buf][rh * 16 + lg * 4];
        acc0[0] *= sc4.x; acc0[1] *= sc4.y; acc0[2] *= sc4.z; acc0[3] *= sc4.w;
        acc1[0] *= sc4.x; acc1[1] *= sc4.y; acc1[2] *= sc4.z; acc1[3] *= sc4.w;

        __builtin_amdgcn_s_setprio(1);
#pragma unroll
        for (int ks = 0; ks < 4; ++ks) {
            acc0 = __builtin_amdgcn_mfma_f32_16x16x32_bf16(pa[ks], vb0[ks], acc0, 0, 0, 0);
            acc1 = __builtin_amdgcn_mfma_f32_16x16x32_bf16(pa[ks], vb1[ks], acc1, 0, 0, 0);
        }
        __builtin_amdgcn_s_setprio(0);
    }

    // ---- epilogue: out = acc / l + bias ----
    float4 lw = *(const float4*)&lrow[rh * 16 + lg * 4];
    const int c = wv * 32 + ll;
    const float bv0 = bias[c];
    const float bv1 = bias[c + 16];

    float* o = out + ((size_t)(b * N_ + i0 + rh * 16 + lg * 4)) * C_ + c;
    o[0 * C_]      = acc0[0] / lw.x + bv0;
    o[1 * C_]      = acc0[1] / lw.y + bv0;
    o[2 * C_]      = acc0[2] / lw.z + bv0;
    o[3 * C_]      = acc0[3] / lw.w + bv0;
    o[0 * C_ + 16] = acc1[0] / lw.x + bv1;
    o[1 * C_ + 16] = acc1[1] / lw.y + bv1;
    o[2 * C_ + 16] = acc1[2] / lw.z + bv1;
    o[3 * C_ + 16] = acc1[3] / lw.w + bv1;
}

extern "C" void kernel_launch(void* const* d_in, const int* in_sizes, int n_in,
                              void* d_out, int out_size, void* d_ws, size_t ws_size,
                              hipStream_t stream) {
    const float* x    = (const float*)d_in[0];
    const int*   adj  = (const int*)d_in[1];
    const float* W    = (const float*)d_in[2];
    const float* a    = (const float*)d_in[3];
    const float* bias = (const float*)d_in[4];
    float* out = (float*)d_out;

    char* ws = (char*)d_ws;
    unsigned short* hT = (unsigned short*)ws;                        // 4 MB bf16 [B,C,N]
    float* at1 = (float*)(ws + (size_t)4 * 1024 * 1024);             // 64 KB
    float* at2 = (float*)(ws + (size_t)4 * 1024 * 1024 + 64 * 1024); // 64 KB

    k1_hidden<<<(B_ * N_) / 64, 256, 0, stream>>>(x, W, a, hT, at1, at2);
    k2_attn<<<B_ * (N_ / IB), 512, 0, stream>>>(adj, hT, at1, at2, bias, out);
}